// Round 7
// baseline (11863.682 us; speedup 1.0000x reference)
//
#include <hip/hip_runtime.h>

#define NB 32
#define T 256
#define NS 64
#define NC 32
#define NSC 96

#define COMP(v,i) ((i)==0?(v).x:((i)==1?(v).y:((i)==2?(v).z:(v).w)))

static __device__ __forceinline__ float dot4(float4 a, float4 b){
    return fmaf(a.x,b.x, fmaf(a.y,b.y, fmaf(a.z,b.z, a.w*b.w)));
}
static __device__ __forceinline__ float bcastf(float v, int l){
    return __int_as_float(__builtin_amdgcn_readlane(__float_as_int(v), l));
}

// Static device-global workspace; fully rewritten every call -> deterministic.
__device__ __align__(16) float g_KtG[(size_t)NB*T*NS*NC];   // [b][t][s][u], Kt[s][u]=K[u][s]
__device__ __align__(16) float g_kkG[(size_t)NB*T*NC];      // [b][t][u]

// ---------------------------------------------------------------------------
// Backward Riccati (policy-evaluation form; same math as the R5/R6 pass).
// One block (512 threads) per batch. ~111 KB LDS, 1 block/CU.
// ---------------------------------------------------------------------------
__global__ __launch_bounds__(512, 2)
void lqr_bwd(const float* __restrict__ Qg_, const float* __restrict__ pg_,
             const float* __restrict__ Ag_, const float* __restrict__ Bg_,
             const float* __restrict__ c1g_, const float* __restrict__ x0g_,
             float* __restrict__ outc)
{
    __shared__ __align__(16) float Fo[64][100];  // F[s][j] (A|B), j<96
    __shared__ __align__(16) float V[64][68];    // carry V; holds Qxx between P2 and P6
    __shared__ __align__(16) float W[64][100];   // W = V*F
    __shared__ __align__(16) float Qxu[64][36];
    __shared__ __align__(16) float QuuC[32][36]; // Quu copy (survives GJ)
    __shared__ __align__(16) float Maug[32][68]; // in: Quu (cols 0:32); out: Minv (cols 32:64)
    __shared__ __align__(16) float Kt[64][36];   // Kt[s][u] = K[u][s]
    __shared__ __align__(16) float Gt[64][36];   // Gt[j][u] = (Quu*K)[u][j]
    __shared__ __align__(16) float qh[96];
    __shared__ __align__(16) float hbuf[32];     // h = qu + Quu*kk
    __shared__ __align__(16) float c1l[64];
    __shared__ __align__(16) float vl[64];
    __shared__ __align__(16) float kkl[32];
    __shared__ __align__(16) float x0l[64];
    __shared__ float wAcc;

    const int tid = threadIdx.x;
    const int b   = blockIdx.x;

    const float* Qg = Qg_ + (size_t)b*T*NSC*NSC;
    const float* pg = pg_ + (size_t)b*T*NSC;
    const float* Ag = Ag_ + (size_t)b*NS*NS;
    const float* Bg = Bg_ + (size_t)b*NS*NC;
    float* KtG = g_KtG + (size_t)b*T*NS*NC;
    float* kkG = g_kkG + (size_t)b*T*NC;

    // ---- init
    for (int e = tid; e < NS*NS; e += 512) { int s = e>>6, j = e&63; Fo[s][j] = Ag[e]; }
    for (int e = tid; e < NS*NC; e += 512) { int s = e>>5, u = e&31; Fo[s][64+u] = Bg[e]; }
    for (int e = tid; e < 64*68; e += 512) ((float*)V)[e] = 0.f;
    if (tid < 64) { c1l[tid] = c1g_[b*64+tid]; vl[tid] = 0.f; x0l[tid] = x0g_[b*64+tid]; }
    if (tid == 0) wAcc = 0.f;
    __syncthreads();

    for (int t = T-1; t >= 0; --t) {
        const float* Qt = Qg + (size_t)t*NSC*NSC;
        const float* pt = pg + (size_t)t*NSC;

        // ---- prefetch Qt tiles into registers (consumed in P2; hidden under P1)
        float4 pfa[4], pfb[4];
        float ptj = 0.f;
        if (tid < 128) {                       // Qxx tile rows/cols
            const int i0 = (tid & 15)*4, j0 = (tid >> 4)*8;
            #pragma unroll
            for (int r = 0; r < 4; ++r) {
                pfa[r] = *(const float4*)&Qt[(size_t)(i0+r)*96 + j0];
                pfb[r] = *(const float4*)&Qt[(size_t)(i0+r)*96 + j0 + 4];
            }
        } else if (tid < 192) {                // Qxu tile
            const int l = tid-128, i0 = (l & 15)*4, u0 = (l >> 4)*8;
            #pragma unroll
            for (int r = 0; r < 4; ++r) {
                pfa[r] = *(const float4*)&Qt[(size_t)(i0+r)*96 + 64 + u0];
                pfb[r] = *(const float4*)&Qt[(size_t)(i0+r)*96 + 64 + u0 + 4];
            }
        } else if (tid < 224) {                // Quu tile
            const int l = tid-192, w0 = (l & 7)*4, u0 = (l >> 3)*8;
            #pragma unroll
            for (int r = 0; r < 4; ++r) {
                pfa[r] = *(const float4*)&Qt[(size_t)(64+w0+r)*96 + 64 + u0];
                pfb[r] = *(const float4*)&Qt[(size_t)(64+w0+r)*96 + 64 + u0 + 4];
            }
        } else if (tid >= 256 && tid < 352) {  // qh
            ptj = pt[tid-256];
        }

        // ---- P0 (wave 0, no barrier needed): wAcc += 0.5*c1'Vc1 + v'c1
        if (tid < 64) {
            float d = 0.f;
            #pragma unroll
            for (int k4 = 0; k4 < 16; ++k4)
                d += dot4(*(const float4*)&V[tid][k4*4], *(const float4*)&c1l[k4*4]);
            float ps = c1l[tid]*(0.5f*d + vl[tid]);
            ps += __shfl_xor(ps,32); ps += __shfl_xor(ps,16); ps += __shfl_xor(ps,8);
            ps += __shfl_xor(ps,4);  ps += __shfl_xor(ps,2);  ps += __shfl_xor(ps,1);
            if (tid == 0) wAcc += ps;
        }

        // ---- P1: W[s][j] = sum_k V[k][s]*Fo[k][j]  (V symmetric => W = V*F)
        if (tid < 192) {
            const int r0 = (tid & 15)*4, c0 = (tid >> 4)*8;
            float acc[4][8] = {};
            #pragma unroll 4
            for (int k = 0; k < 64; ++k) {
                const float4 v4 = *(const float4*)&V[k][r0];
                const float4 fa = *(const float4*)&Fo[k][c0];
                const float4 fb = *(const float4*)&Fo[k][c0+4];
                #pragma unroll
                for (int r = 0; r < 4; ++r) {
                    const float vr = COMP(v4,r);
                    acc[r][0] = fmaf(vr, fa.x, acc[r][0]);
                    acc[r][1] = fmaf(vr, fa.y, acc[r][1]);
                    acc[r][2] = fmaf(vr, fa.z, acc[r][2]);
                    acc[r][3] = fmaf(vr, fa.w, acc[r][3]);
                    acc[r][4] = fmaf(vr, fb.x, acc[r][4]);
                    acc[r][5] = fmaf(vr, fb.y, acc[r][5]);
                    acc[r][6] = fmaf(vr, fb.z, acc[r][6]);
                    acc[r][7] = fmaf(vr, fb.w, acc[r][7]);
                }
            }
            #pragma unroll
            for (int r = 0; r < 4; ++r) {
                *(float4*)&W[r0+r][c0]   = make_float4(acc[r][0],acc[r][1],acc[r][2],acc[r][3]);
                *(float4*)&W[r0+r][c0+4] = make_float4(acc[r][4],acc[r][5],acc[r][6],acc[r][7]);
            }
        }
        __syncthreads();

        // ---- P2: Qh = Qt + F'W (4x8 tiles) ; qh = pt + W'c1 + F'v
        if (tid < 224) {
            const float4* fcol; const float4* wa_base; // roles per group
            int i0, j0, outsel;
            if (tid < 128)      { i0 = (tid & 15)*4;        j0 = (tid >> 4)*8;        outsel = 0; }
            else if (tid < 192) { const int l = tid-128; i0 = (l & 15)*4; j0 = 64 + (l >> 4)*8; outsel = 1; }
            else                { const int l = tid-192; i0 = 64 + (l & 7)*4; j0 = 64 + (l >> 3)*8; outsel = 2; }
            float acc[4][8] = {};
            #pragma unroll 4
            for (int s = 0; s < 64; ++s) {
                const float4 f4 = *(const float4*)&Fo[s][i0];
                const float4 wa = *(const float4*)&W[s][j0];
                const float4 wb = *(const float4*)&W[s][j0+4];
                #pragma unroll
                for (int r = 0; r < 4; ++r) {
                    const float fr = COMP(f4,r);
                    acc[r][0] = fmaf(fr, wa.x, acc[r][0]);
                    acc[r][1] = fmaf(fr, wa.y, acc[r][1]);
                    acc[r][2] = fmaf(fr, wa.z, acc[r][2]);
                    acc[r][3] = fmaf(fr, wa.w, acc[r][3]);
                    acc[r][4] = fmaf(fr, wb.x, acc[r][4]);
                    acc[r][5] = fmaf(fr, wb.y, acc[r][5]);
                    acc[r][6] = fmaf(fr, wb.z, acc[r][6]);
                    acc[r][7] = fmaf(fr, wb.w, acc[r][7]);
                }
            }
            #pragma unroll
            for (int r = 0; r < 4; ++r) {
                const float4 lo = make_float4(acc[r][0]+pfa[r].x, acc[r][1]+pfa[r].y,
                                              acc[r][2]+pfa[r].z, acc[r][3]+pfa[r].w);
                const float4 hi = make_float4(acc[r][4]+pfb[r].x, acc[r][5]+pfb[r].y,
                                              acc[r][6]+pfb[r].z, acc[r][7]+pfb[r].w);
                if (outsel == 0) {
                    *(float4*)&V[i0+r][j0]   = lo;   // Qxx in place (old V dead)
                    *(float4*)&V[i0+r][j0+4] = hi;
                } else if (outsel == 1) {
                    *(float4*)&Qxu[i0+r][j0-64]   = lo;
                    *(float4*)&Qxu[i0+r][j0-64+4] = hi;
                } else {
                    const int w = i0-64 + r, u = j0-64;
                    *(float4*)&Maug[w][u]   = lo;  *(float4*)&Maug[w][u+4]  = hi;
                    *(float4*)&QuuC[w][u]   = lo;  *(float4*)&QuuC[w][u+4]  = hi;
                }
            }
        } else if (tid >= 256 && tid < 352) {
            const int j = tid - 256;
            float q = ptj;
            #pragma unroll 4
            for (int s = 0; s < 64; ++s) {
                q = fmaf(W[s][j],  c1l[s], q);
                q = fmaf(Fo[s][j], vl[s],  q);
            }
            qh[j] = q;
        }
        __syncthreads();

        // ---- P3: Gauss-Jordan inverse of Quu on wave 0, columns-in-registers.
        // lane l holds column l of [Quu | I] (32 regs). Zero barriers.
        if (tid < 64) {
            float m[32];
            if (tid < 32) {
                #pragma unroll
                for (int u = 0; u < 32; ++u) m[u] = Maug[u][tid];
            } else {
                #pragma unroll
                for (int u = 0; u < 32; ++u) m[u] = (u == tid-32) ? 1.f : 0.f;
            }
            #pragma unroll
            for (int k = 0; k < 32; ++k) {
                const float pinv = 1.0f / bcastf(m[k], k);
                m[k] *= pinv;
                #pragma unroll
                for (int u = 0; u < 32; ++u) {
                    if (u == k) continue;
                    const float f = bcastf(m[u], k);   // pre-update A[u][k] from lane k
                    m[u] = fmaf(-f, m[k], m[u]);
                }
            }
            if (tid >= 32) {
                #pragma unroll
                for (int u = 0; u < 32; ++u) Maug[u][tid] = m[u];  // Minv cols at 32..63
            }
        }
        __syncthreads();

        // ---- P4: Kt[i][u] = -sum_w Qxu[i][w]*Minv[u][w] (4x8); kk = -Minv*qu
        if (tid < 64) {
            const int i0 = (tid & 15)*4, u0 = (tid >> 4)*8;
            float acc[4][8] = {};
            #pragma unroll
            for (int w4 = 0; w4 < 8; ++w4) {
                const int wb = w4*4;
                float4 q[4];
                #pragma unroll
                for (int r = 0; r < 4; ++r) q[r] = *(const float4*)&Qxu[i0+r][wb];
                #pragma unroll
                for (int c = 0; c < 8; ++c) {
                    const float4 mv = *(const float4*)&Maug[u0+c][32+wb];
                    #pragma unroll
                    for (int r = 0; r < 4; ++r) acc[r][c] -= dot4(q[r], mv);
                }
            }
            #pragma unroll
            for (int r = 0; r < 4; ++r) {
                const float4 lo = make_float4(acc[r][0],acc[r][1],acc[r][2],acc[r][3]);
                const float4 hi = make_float4(acc[r][4],acc[r][5],acc[r][6],acc[r][7]);
                *(float4*)&Kt[i0+r][u0]   = lo;
                *(float4*)&Kt[i0+r][u0+4] = hi;
                *(float4*)&KtG[(size_t)t*2048 + (i0+r)*32 + u0]     = lo;
                *(float4*)&KtG[(size_t)t*2048 + (i0+r)*32 + u0 + 4] = hi;
            }
        } else if (tid < 96) {
            const int u = tid - 64;
            float ka = 0.f;
            #pragma unroll
            for (int w4 = 0; w4 < 8; ++w4)
                ka -= dot4(*(const float4*)&Maug[u][32+w4*4], *(const float4*)&qh[64+w4*4]);
            kkl[u] = ka;
            kkG[t*32 + u] = ka;
        }
        __syncthreads();

        // ---- P5: Gt[j][u] = sum_w QuuC[u][w]*Kt[j][w] (4x8); h = qu + Quu*kk
        if (tid < 64) {
            const int j0 = (tid & 15)*4, u0 = (tid >> 4)*8;
            float acc[4][8] = {};
            #pragma unroll
            for (int w4 = 0; w4 < 8; ++w4) {
                const int wb = w4*4;
                float4 kt[4];
                #pragma unroll
                for (int r = 0; r < 4; ++r) kt[r] = *(const float4*)&Kt[j0+r][wb];
                #pragma unroll
                for (int c = 0; c < 8; ++c) {
                    const float4 qu4 = *(const float4*)&QuuC[u0+c][wb];
                    #pragma unroll
                    for (int r = 0; r < 4; ++r) acc[r][c] += dot4(kt[r], qu4);
                }
            }
            #pragma unroll
            for (int r = 0; r < 4; ++r) {
                *(float4*)&Gt[j0+r][u0]   = make_float4(acc[r][0],acc[r][1],acc[r][2],acc[r][3]);
                *(float4*)&Gt[j0+r][u0+4] = make_float4(acc[r][4],acc[r][5],acc[r][6],acc[r][7]);
            }
        } else if (tid < 96) {
            const int u = tid - 64;
            float h = qh[64+u];
            #pragma unroll
            for (int w4 = 0; w4 < 8; ++w4)
                h += dot4(*(const float4*)&QuuC[u][w4*4], *(const float4*)&kkl[w4*4]);
            hbuf[u] = h;
        }
        __syncthreads();

        // ---- P6: V <- Qxx + Qxu*K + K'Qux + K'QuuK (4x8 tiles, 128 thr);
        //          vn (64 thr); wAcc term (32 thr)
        if (tid < 128) {
            const int i0 = (tid & 15)*4, j0 = (tid >> 4)*8;
            float acc[4][8];
            #pragma unroll
            for (int r = 0; r < 4; ++r) {
                const float4 a = *(const float4*)&V[i0+r][j0];
                const float4 bq = *(const float4*)&V[i0+r][j0+4];
                acc[r][0]=a.x; acc[r][1]=a.y; acc[r][2]=a.z; acc[r][3]=a.w;
                acc[r][4]=bq.x; acc[r][5]=bq.y; acc[r][6]=bq.z; acc[r][7]=bq.w;
            }
            #pragma unroll
            for (int u4 = 0; u4 < 8; ++u4) {
                const int ub = u4*4;
                float4 xui[4], kti[4];
                #pragma unroll
                for (int r = 0; r < 4; ++r) {
                    xui[r] = *(const float4*)&Qxu[i0+r][ub];
                    kti[r] = *(const float4*)&Kt[i0+r][ub];
                }
                #pragma unroll
                for (int c = 0; c < 8; ++c) {
                    const float4 ktj = *(const float4*)&Kt[j0+c][ub];
                    const float4 xuj = *(const float4*)&Qxu[j0+c][ub];
                    const float4 gtj = *(const float4*)&Gt[j0+c][ub];
                    #pragma unroll
                    for (int r = 0; r < 4; ++r)
                        acc[r][c] += dot4(xui[r],ktj) + dot4(kti[r],xuj) + dot4(kti[r],gtj);
                }
            }
            #pragma unroll
            for (int r = 0; r < 4; ++r) {
                *(float4*)&V[i0+r][j0]   = make_float4(acc[r][0],acc[r][1],acc[r][2],acc[r][3]);
                *(float4*)&V[i0+r][j0+4] = make_float4(acc[r][4],acc[r][5],acc[r][6],acc[r][7]);
            }
        } else if (tid < 192) {
            const int l = tid - 128;
            float vv = qh[l];
            #pragma unroll
            for (int u4 = 0; u4 < 8; ++u4) {
                vv += dot4(*(const float4*)&Qxu[l][u4*4], *(const float4*)&kkl[u4*4]);
                vv += dot4(*(const float4*)&Kt[l][u4*4],  *(const float4*)&hbuf[u4*4]);
            }
            vl[l] = vv;
        } else if (tid < 224) {
            const int u = tid - 192;
            float r = kkl[u]*(hbuf[u] + qh[64+u]);
            r += __shfl_xor(r,16); r += __shfl_xor(r,8); r += __shfl_xor(r,4);
            r += __shfl_xor(r,2);  r += __shfl_xor(r,1);
            if (u == 0) wAcc += 0.5f*r;
        }
        __syncthreads();

        // ---- symmetrize V
        for (int e = tid; e < 4096; e += 512) {
            const int i = e >> 6, j = e & 63;
            if (i < j) {
                const float av = 0.5f*(V[i][j] + V[j][i]);
                V[i][j] = av; V[j][i] = av;
            }
        }
        __syncthreads();
    }

    // ---- cost[b] = wAcc + 0.5*x0'V0 x0 + v0'x0
    if (tid < 64) {
        float rd = 0.f;
        #pragma unroll
        for (int k4 = 0; k4 < 16; ++k4)
            rd += dot4(*(const float4*)&V[tid][k4*4], *(const float4*)&x0l[k4*4]);
        float ps = x0l[tid]*(0.5f*rd + vl[tid]);
        ps += __shfl_xor(ps,32); ps += __shfl_xor(ps,16); ps += __shfl_xor(ps,8);
        ps += __shfl_xor(ps,4);  ps += __shfl_xor(ps,2);  ps += __shfl_xor(ps,1);
        if (tid == 0) outc[b] = wAcc + ps;
    }
}

// ---------------------------------------------------------------------------
// Forward rollout: one block (64 threads) per batch.
// ---------------------------------------------------------------------------
__global__ __launch_bounds__(64)
void lqr_fwd(const float* __restrict__ Ag_, const float* __restrict__ Bg_,
             const float* __restrict__ c1g_, const float* __restrict__ x0g_,
             float* __restrict__ outx, float* __restrict__ outu)
{
    __shared__ __align__(16) float At[64][68];
    __shared__ __align__(16) float Bt[32][68];
    __shared__ __align__(16) float KtL[64][36];
    __shared__ float xl[64], ul[32], cl[64];

    const int lane = threadIdx.x;
    const int b = blockIdx.x;

    const float* KtG = g_KtG + (size_t)b*T*NS*NC;
    const float* kkG = g_kkG + (size_t)b*T*NC;

    for (int e = lane; e < NS*NS; e += 64) { int i = e>>6, j = e&63; At[j][i] = Ag_[(size_t)b*4096 + e]; }
    for (int e = lane; e < NS*NC; e += 64) { int i = e>>5, w = e&31; Bt[w][i] = Bg_[(size_t)b*2048 + e]; }
    xl[lane] = x0g_[b*64 + lane];
    cl[lane] = c1g_[b*64 + lane];
    __syncthreads();

    for (int t = 0; t < T; ++t) {
        #pragma unroll
        for (int r = 0; r < 8; ++r) {
            const int idx = r*256 + lane*4;
            const float4 g = *(const float4*)&KtG[(size_t)t*2048 + idx];
            *(float4*)&KtL[idx >> 5][idx & 31] = g;
        }
        const float ku = (lane < 32) ? kkG[t*32 + lane] : 0.f;
        __syncthreads();

        outx[((size_t)b*T + t)*64 + lane] = xl[lane];
        if (lane < 32) {
            float uu = ku;
            #pragma unroll 16
            for (int s = 0; s < 64; ++s) uu = fmaf(KtL[s][lane], xl[s], uu);
            ul[lane] = uu;
            outu[((size_t)b*T + t)*32 + lane] = uu;
        }
        __syncthreads();

        float xn = cl[lane];
        #pragma unroll 16
        for (int j = 0; j < 64; ++j) xn = fmaf(At[j][lane], xl[j], xn);
        #pragma unroll
        for (int w = 0; w < 32; ++w) xn = fmaf(Bt[w][lane], ul[w], xn);
        __syncthreads();
        xl[lane] = xn;
        __syncthreads();
    }
}

// ---------------------------------------------------------------------------
extern "C" void kernel_launch(void* const* d_in, const int* in_sizes, int n_in,
                              void* d_out, int out_size, void* d_ws, size_t ws_size,
                              hipStream_t stream)
{
    const float* Q  = (const float*)d_in[0];
    const float* p  = (const float*)d_in[1];
    const float* A  = (const float*)d_in[2];
    const float* B  = (const float*)d_in[3];
    const float* c1 = (const float*)d_in[4];
    const float* x0 = (const float*)d_in[5];

    float* outx = (float*)d_out;                       // (NB,T,NS)
    float* outu = outx + (size_t)NB*T*NS;              // (NB,T,NC)
    float* outc = outu + (size_t)NB*T*NC;              // (NB,)

    lqr_bwd<<<NB, 512, 0, stream>>>(Q, p, A, B, c1, x0, outc);
    lqr_fwd<<<NB, 64, 0, stream>>>(A, B, c1, x0, outx, outu);
}

// Round 8
// 7676.913 us; speedup vs baseline: 1.5454x; 1.5454x over previous
//
#include <hip/hip_runtime.h>

#define NB 32
#define T 256
#define NS 64
#define NC 32
#define NSC 96

#define COMP(v,i) ((i)==0?(v).x:((i)==1?(v).y:((i)==2?(v).z:(v).w)))

static __device__ __forceinline__ float dot4(float4 a, float4 b){
    return fmaf(a.x,b.x, fmaf(a.y,b.y, fmaf(a.z,b.z, a.w*b.w)));
}

// Static device-global workspace; fully rewritten every call -> deterministic.
__device__ __align__(16) float g_KtG[(size_t)NB*T*NS*NC];   // [b][t][s][u], Kt[s][u]=K[u][s]
__device__ __align__(16) float g_kkG[(size_t)NB*T*NC];      // [b][t][u]

// ---------------------------------------------------------------------------
// Backward Riccati (policy-evaluation form; numerics identical to R5/R6 pass).
// One block (512 threads) per batch; all heavy phases keep 512 active threads.
// ---------------------------------------------------------------------------
__global__ __launch_bounds__(512, 2)
void lqr_bwd(const float* __restrict__ Qg_, const float* __restrict__ pg_,
             const float* __restrict__ Ag_, const float* __restrict__ Bg_,
             const float* __restrict__ c1g_, const float* __restrict__ x0g_,
             float* __restrict__ outc)
{
    __shared__ __align__(16) float Fo[64][100];  // F[s][j] (A|B), j<96
    __shared__ __align__(16) float V[64][68];    // carry V; holds Qxx between P2 and P6
    __shared__ __align__(16) float W[64][100];   // W = V*F
    __shared__ __align__(16) float Qxu[64][36];
    __shared__ __align__(16) float QuuC[32][36]; // Quu copy (survives GJ)
    __shared__ __align__(16) float Maug[32][68]; // P2 writes Quu (cols 0:32); GJ writes Minv (cols 32:64)
    __shared__ __align__(16) float Kt[64][36];   // Kt[s][u] = K[u][s]
    __shared__ __align__(16) float Rt[64][36];   // Rt[j][u] = Qux[u][j] + (Quu*K)[u][j]
    __shared__ __align__(16) float prow[2][64];  // GJ pivot row (double-buffered)
    __shared__ __align__(16) float pfac[2][32];  // GJ pivot column
    __shared__ __align__(16) float qh[96];
    __shared__ __align__(16) float hbuf[32];     // h = qu + Quu*kk
    __shared__ __align__(16) float c1l[64];
    __shared__ __align__(16) float vl[64];
    __shared__ __align__(16) float kkl[32];
    __shared__ __align__(16) float x0l[64];
    __shared__ float wAcc;

    const int tid = threadIdx.x;
    const int b   = blockIdx.x;

    const float* Qg = Qg_ + (size_t)b*T*NSC*NSC;
    const float* pg = pg_ + (size_t)b*T*NSC;
    const float* Ag = Ag_ + (size_t)b*NS*NS;
    const float* Bg = Bg_ + (size_t)b*NS*NC;
    float* KtG = g_KtG + (size_t)b*T*NS*NC;
    float* kkG = g_kkG + (size_t)b*T*NC;

    // ---- init
    for (int e = tid; e < NS*NS; e += 512) { int s = e>>6, j = e&63; Fo[s][j] = Ag[e]; }
    for (int e = tid; e < NS*NC; e += 512) { int s = e>>5, u = e&31; Fo[s][64+u] = Bg[e]; }
    for (int e = tid; e < 64*68; e += 512) ((float*)V)[e] = 0.f;
    if (tid < 64) { c1l[tid] = c1g_[b*64+tid]; vl[tid] = 0.f; x0l[tid] = x0g_[b*64+tid]; }
    if (tid == 0) wAcc = 0.f;
    __syncthreads();

    const int jc = tid & 31;          // column (P1/P2 GEMM)
    const int r0 = (tid >> 5) * 4;    // 4 rows per thread
    const int wq = tid >> 4;          // Quu row (P2), GJ row
    const int uq = (tid & 15) * 2;    // Quu col pair (P2)
    const int gjq = tid & 15, gj0 = gjq * 4;  // GJ col group

    for (int t = T-1; t >= 0; --t) {
        const float* Qt = Qg + (size_t)t*NSC*NSC;
        const float* pt = pg + (size_t)t*NSC;

        // ---- P1: W[s][j] = sum_k V[k][s]*Fo[k][j] (V symmetric => W = V*F);
        //          threads 0..63 also: wAcc += 0.5*c1'Vc1 + v'c1
        {
            float aA[4] = {}, aB[4] = {}, aC[4] = {};
            for (int k = 0; k < 64; ++k) {
                const float4 v4 = *(const float4*)&V[k][r0];
                const float fA = Fo[k][jc], fB = Fo[k][32+jc], fC = Fo[k][64+jc];
                aA[0]=fmaf(v4.x,fA,aA[0]); aA[1]=fmaf(v4.y,fA,aA[1]);
                aA[2]=fmaf(v4.z,fA,aA[2]); aA[3]=fmaf(v4.w,fA,aA[3]);
                aB[0]=fmaf(v4.x,fB,aB[0]); aB[1]=fmaf(v4.y,fB,aB[1]);
                aB[2]=fmaf(v4.z,fB,aB[2]); aB[3]=fmaf(v4.w,fB,aB[3]);
                aC[0]=fmaf(v4.x,fC,aC[0]); aC[1]=fmaf(v4.y,fC,aC[1]);
                aC[2]=fmaf(v4.z,fC,aC[2]); aC[3]=fmaf(v4.w,fC,aC[3]);
            }
            #pragma unroll
            for (int r = 0; r < 4; ++r) {
                W[r0+r][jc]    = aA[r];
                W[r0+r][32+jc] = aB[r];
                W[r0+r][64+jc] = aC[r];
            }
        }
        if (tid < 64) {
            float d = 0.f;
            #pragma unroll
            for (int k4 = 0; k4 < 16; ++k4)
                d += dot4(*(const float4*)&V[tid][k4*4], *(const float4*)&c1l[k4*4]);
            float ps = c1l[tid]*(0.5f*d + vl[tid]);
            ps += __shfl_xor(ps,32); ps += __shfl_xor(ps,16); ps += __shfl_xor(ps,8);
            ps += __shfl_xor(ps,4);  ps += __shfl_xor(ps,2);  ps += __shfl_xor(ps,1);
            if (tid == 0) wAcc += ps;
        }
        __syncthreads();

        // ---- P2 (fused, 512 thr): Qh = Qt + F'W  -> Qxx into V (in place),
        //      Qxu, Quu -> Maug cols 0:32 + QuuC; qh = pt + W'c1 + F'v (thr<96);
        //      GJ pivot-0 staging (prow/pfac) for free.
        {
            float qtA[4], qtB[4], qtC[4];
            #pragma unroll
            for (int r = 0; r < 4; ++r) {
                qtA[r] = Qt[(size_t)(r0+r)*96 + jc];
                qtB[r] = Qt[(size_t)(r0+r)*96 + 32 + jc];
                qtC[r] = Qt[(size_t)(r0+r)*96 + 64 + jc];
            }
            const float qq0 = Qt[(size_t)(64+wq)*96 + 64 + uq];
            const float qq1 = Qt[(size_t)(64+wq)*96 + 64 + uq + 1];
            const float ptv = (tid < 96) ? pt[tid] : 0.f;

            float aA[4] = {}, aB[4] = {}, aC[4] = {};
            float q0 = 0.f, q1 = 0.f, qacc = 0.f;
            for (int s = 0; s < 64; ++s) {
                const float4 f4 = *(const float4*)&Fo[s][r0];
                const float wA = W[s][jc], wB = W[s][32+jc], wC = W[s][64+jc];
                aA[0]=fmaf(f4.x,wA,aA[0]); aA[1]=fmaf(f4.y,wA,aA[1]);
                aA[2]=fmaf(f4.z,wA,aA[2]); aA[3]=fmaf(f4.w,wA,aA[3]);
                aB[0]=fmaf(f4.x,wB,aB[0]); aB[1]=fmaf(f4.y,wB,aB[1]);
                aB[2]=fmaf(f4.z,wB,aB[2]); aB[3]=fmaf(f4.w,wB,aB[3]);
                aC[0]=fmaf(f4.x,wC,aC[0]); aC[1]=fmaf(f4.y,wC,aC[1]);
                aC[2]=fmaf(f4.z,wC,aC[2]); aC[3]=fmaf(f4.w,wC,aC[3]);
                const float fb = Fo[s][64+wq];
                q0 = fmaf(fb, W[s][64+uq],   q0);
                q1 = fmaf(fb, W[s][64+uq+1], q1);
                if (tid < 96) {
                    const float qv = (tid < 32) ? wA : ((tid < 64) ? wB : wC);
                    qacc = fmaf(qv, c1l[s], qacc);
                    qacc = fmaf(Fo[s][tid], vl[s], qacc);
                }
            }
            #pragma unroll
            for (int r = 0; r < 4; ++r) {
                V[r0+r][jc]    = aA[r] + qtA[r];   // Qxx in place (old V dead)
                V[r0+r][32+jc] = aB[r] + qtB[r];
                Qxu[r0+r][jc]  = aC[r] + qtC[r];
            }
            q0 += qq0; q1 += qq1;
            Maug[wq][uq]   = q0;  Maug[wq][uq+1] = q1;
            QuuC[wq][uq]   = q0;  QuuC[wq][uq+1] = q1;
            if (wq == 0) {        // GJ pivot-0 row = [Quu[0][:], e0]
                prow[0][uq]   = q0;  prow[0][uq+1]   = q1;
                prow[0][32+uq]   = (uq == 0) ? 1.f : 0.f;
                prow[0][32+uq+1] = 0.f;
            }
            if (uq == 0) pfac[0][wq] = q0;   // col 0 of Quu
            if (tid < 96) qh[tid] = ptv + qacc;
        }
        __syncthreads();

        // ---- P3: Gauss-Jordan of Quu, matrix-in-registers, 1 barrier/pivot.
        // Thread (wq, gjq) owns [Quu|I] row wq, cols gj0..gj0+3 in a float4.
        {
            float4 m;
            if (gjq < 8) m = *(const float4*)&Maug[wq][gj0];
            else {
                const int base = gj0 - 32;
                m.x = (base+0==wq)?1.f:0.f; m.y = (base+1==wq)?1.f:0.f;
                m.z = (base+2==wq)?1.f:0.f; m.w = (base+3==wq)?1.f:0.f;
            }
            #pragma unroll
            for (int k = 0; k < 32; ++k) {
                const int par = k & 1, nxt = par ^ 1;
                const float pinv = 1.0f / prow[par][k];
                const float4 pr = *(const float4*)&prow[par][gj0];
                if (wq == k) {
                    m.x = pr.x*pinv; m.y = pr.y*pinv; m.z = pr.z*pinv; m.w = pr.w*pinv;
                } else {
                    const float fac = pfac[par][wq]*pinv;
                    m.x = fmaf(-fac,pr.x,m.x); m.y = fmaf(-fac,pr.y,m.y);
                    m.z = fmaf(-fac,pr.z,m.z); m.w = fmaf(-fac,pr.w,m.w);
                }
                if (k < 31) {
                    if (wq == k+1) *(float4*)&prow[nxt][gj0] = m;     // stage next pivot row
                    if (((k+1)>>2) == gjq) pfac[nxt][wq] = COMP(m,(k+1)&3); // next pivot col
                } else if (gjq >= 8) {
                    *(float4*)&Maug[wq][gj0] = m;                     // Minv at cols 32:64
                }
                __syncthreads();
            }
        }

        // ---- P4: Kt[i][u] = -sum_w Qxu[i][w]*Minv[u][w]; kk = -Minv*qu
        {
            const int i = tid >> 3, u0 = (tid & 7) * 4;
            float a0=0,a1=0,a2=0,a3=0;
            #pragma unroll
            for (int w4 = 0; w4 < 8; ++w4) {
                const int wb = w4*4;
                const float4 q4 = *(const float4*)&Qxu[i][wb];
                const float4 m0 = *(const float4*)&Maug[u0+0][32+wb];
                const float4 m1 = *(const float4*)&Maug[u0+1][32+wb];
                const float4 m2 = *(const float4*)&Maug[u0+2][32+wb];
                const float4 m3 = *(const float4*)&Maug[u0+3][32+wb];
                a0 -= dot4(q4,m0); a1 -= dot4(q4,m1);
                a2 -= dot4(q4,m2); a3 -= dot4(q4,m3);
            }
            const float4 kt4 = make_float4(a0,a1,a2,a3);
            *(float4*)&Kt[i][u0] = kt4;
            *(float4*)&KtG[(size_t)t*2048 + i*32 + u0] = kt4;
            if (tid < 32) {
                float ka = 0.f;
                #pragma unroll
                for (int w4 = 0; w4 < 8; ++w4)
                    ka -= dot4(*(const float4*)&Maug[tid][32+w4*4], *(const float4*)&qh[64+w4*4]);
                kkl[tid] = ka;
                kkG[t*32 + tid] = ka;
            }
        }
        __syncthreads();

        // ---- P5: Rt[j][u] = Qxu[j][u] + sum_w QuuC[u][w]*Kt[j][w]; h = qu + Quu*kk
        {
            const int j = tid >> 3, u0 = (tid & 7) * 4;
            const float4 qx4 = *(const float4*)&Qxu[j][u0];
            float g0=qx4.x, g1=qx4.y, g2=qx4.z, g3=qx4.w;
            #pragma unroll
            for (int w4 = 0; w4 < 8; ++w4) {
                const int wb = w4*4;
                const float4 k4 = *(const float4*)&Kt[j][wb];
                g0 += dot4(*(const float4*)&QuuC[u0+0][wb], k4);
                g1 += dot4(*(const float4*)&QuuC[u0+1][wb], k4);
                g2 += dot4(*(const float4*)&QuuC[u0+2][wb], k4);
                g3 += dot4(*(const float4*)&QuuC[u0+3][wb], k4);
            }
            *(float4*)&Rt[j][u0] = make_float4(g0,g1,g2,g3);
            if (tid < 32) {
                float h = qh[64+tid];
                #pragma unroll
                for (int w4 = 0; w4 < 8; ++w4)
                    h += dot4(*(const float4*)&QuuC[tid][w4*4], *(const float4*)&kkl[w4*4]);
                hbuf[tid] = h;
            }
        }
        __syncthreads();

        // ---- P6: V <- Qxx + Qxu*K + K'(Qux + Quu*K)  [2-term form, 256 thr 4x4];
        //          vn (thr 256-319); wAcc term (thr 320-351)
        if (tid < 256) {
            const int i0 = (tid & 15)*4, j0 = (tid >> 4)*4;
            float acc[4][4];
            #pragma unroll
            for (int r = 0; r < 4; ++r) {
                const float4 x = *(const float4*)&V[i0+r][j0];
                acc[r][0]=x.x; acc[r][1]=x.y; acc[r][2]=x.z; acc[r][3]=x.w;
            }
            #pragma unroll
            for (int u4 = 0; u4 < 8; ++u4) {
                const int ub = u4*4;
                float4 xui[4], kti[4], ktj[4], rtj[4];
                #pragma unroll
                for (int r = 0; r < 4; ++r) {
                    xui[r] = *(const float4*)&Qxu[i0+r][ub];
                    kti[r] = *(const float4*)&Kt[i0+r][ub];
                    ktj[r] = *(const float4*)&Kt[j0+r][ub];
                    rtj[r] = *(const float4*)&Rt[j0+r][ub];
                }
                #pragma unroll
                for (int r = 0; r < 4; ++r)
                    #pragma unroll
                    for (int c = 0; c < 4; ++c)
                        acc[r][c] += dot4(xui[r],ktj[c]) + dot4(kti[r],rtj[c]);
            }
            #pragma unroll
            for (int r = 0; r < 4; ++r)
                *(float4*)&V[i0+r][j0] = make_float4(acc[r][0],acc[r][1],acc[r][2],acc[r][3]);
        } else if (tid < 320) {
            const int l = tid - 256;
            float vv = qh[l];
            #pragma unroll
            for (int u4 = 0; u4 < 8; ++u4) {
                vv += dot4(*(const float4*)&Qxu[l][u4*4], *(const float4*)&kkl[u4*4]);
                vv += dot4(*(const float4*)&Kt[l][u4*4],  *(const float4*)&hbuf[u4*4]);
            }
            vl[l] = vv;
        } else if (tid < 352) {
            const int u = tid - 320;
            float r = kkl[u]*(hbuf[u] + qh[64+u]);
            r += __shfl_xor(r,16); r += __shfl_xor(r,8); r += __shfl_xor(r,4);
            r += __shfl_xor(r,2);  r += __shfl_xor(r,1);
            if (u == 0) wAcc += 0.5f*r;
        }
        __syncthreads();

        // ---- symmetrize V via 4x4 float4 tile pairs (no strided scalar access)
        if (tid < 256) {
            const int a = tid >> 4, bq = tid & 15;
            if (a < bq) {
                float4 t1[4], t2[4];
                #pragma unroll
                for (int r = 0; r < 4; ++r) {
                    t1[r] = *(const float4*)&V[4*a+r][4*bq];
                    t2[r] = *(const float4*)&V[4*bq+r][4*a];
                }
                #pragma unroll
                for (int r = 0; r < 4; ++r) {
                    float4 o, p;
                    o.x = 0.5f*(COMP(t1[r],0)+COMP(t2[0],r));
                    o.y = 0.5f*(COMP(t1[r],1)+COMP(t2[1],r));
                    o.z = 0.5f*(COMP(t1[r],2)+COMP(t2[2],r));
                    o.w = 0.5f*(COMP(t1[r],3)+COMP(t2[3],r));
                    p.x = 0.5f*(COMP(t2[r],0)+COMP(t1[0],r));
                    p.y = 0.5f*(COMP(t2[r],1)+COMP(t1[1],r));
                    p.z = 0.5f*(COMP(t2[r],2)+COMP(t1[2],r));
                    p.w = 0.5f*(COMP(t2[r],3)+COMP(t1[3],r));
                    *(float4*)&V[4*a+r][4*bq] = o;
                    *(float4*)&V[4*bq+r][4*a] = p;
                }
            } else if (a == bq) {
                float4 t1[4];
                #pragma unroll
                for (int r = 0; r < 4; ++r) t1[r] = *(const float4*)&V[4*a+r][4*a];
                #pragma unroll
                for (int r = 0; r < 4; ++r) {
                    float4 o;
                    o.x = 0.5f*(COMP(t1[r],0)+COMP(t1[0],r));
                    o.y = 0.5f*(COMP(t1[r],1)+COMP(t1[1],r));
                    o.z = 0.5f*(COMP(t1[r],2)+COMP(t1[2],r));
                    o.w = 0.5f*(COMP(t1[r],3)+COMP(t1[3],r));
                    *(float4*)&V[4*a+r][4*a] = o;
                }
            }
        }
        __syncthreads();
    }

    // ---- cost[b] = wAcc + 0.5*x0'V0 x0 + v0'x0
    if (tid < 64) {
        float rd = 0.f;
        #pragma unroll
        for (int k4 = 0; k4 < 16; ++k4)
            rd += dot4(*(const float4*)&V[tid][k4*4], *(const float4*)&x0l[k4*4]);
        float ps = x0l[tid]*(0.5f*rd + vl[tid]);
        ps += __shfl_xor(ps,32); ps += __shfl_xor(ps,16); ps += __shfl_xor(ps,8);
        ps += __shfl_xor(ps,4);  ps += __shfl_xor(ps,2);  ps += __shfl_xor(ps,1);
        if (tid == 0) outc[b] = wAcc + ps;
    }
}

// ---------------------------------------------------------------------------
// Forward rollout: one block (64 threads) per batch; K double-buffered with
// next-step prefetch issued before current-step compute (latency hiding).
// ---------------------------------------------------------------------------
__global__ __launch_bounds__(64)
void lqr_fwd(const float* __restrict__ Ag_, const float* __restrict__ Bg_,
             const float* __restrict__ c1g_, const float* __restrict__ x0g_,
             float* __restrict__ outx, float* __restrict__ outu)
{
    __shared__ __align__(16) float At[64][68];
    __shared__ __align__(16) float Bt[32][68];
    __shared__ __align__(16) float KtL[2][64][36];
    __shared__ float xl[64], ul[32], cl[64];

    const int lane = threadIdx.x;
    const int b = blockIdx.x;

    const float* KtG = g_KtG + (size_t)b*T*NS*NC;
    const float* kkG = g_kkG + (size_t)b*T*NC;

    for (int e = lane; e < NS*NS; e += 64) { int i = e>>6, j = e&63; At[j][i] = Ag_[(size_t)b*4096 + e]; }
    for (int e = lane; e < NS*NC; e += 64) { int i = e>>5, w = e&31; Bt[w][i] = Bg_[(size_t)b*2048 + e]; }
    xl[lane] = x0g_[b*64 + lane];
    cl[lane] = c1g_[b*64 + lane];

    // prologue: stage K(0)
    float4 g[8]; float kun = 0.f;
    #pragma unroll
    for (int r = 0; r < 8; ++r) g[r] = *(const float4*)&KtG[r*256 + lane*4];
    if (lane < 32) kun = kkG[lane];
    #pragma unroll
    for (int r = 0; r < 8; ++r) {
        const int idx = r*256 + lane*4;
        *(float4*)&KtL[0][idx >> 5][idx & 31] = g[r];
    }
    float kuc = kun;
    __syncthreads();

    for (int t = 0; t < T; ++t) {
        const int cur = t & 1;
        // issue next-step loads (hidden under this step's compute)
        if (t+1 < T) {
            #pragma unroll
            for (int r = 0; r < 8; ++r)
                g[r] = *(const float4*)&KtG[(size_t)(t+1)*2048 + r*256 + lane*4];
            if (lane < 32) kun = kkG[(t+1)*32 + lane];
        }

        outx[((size_t)b*T + t)*64 + lane] = xl[lane];
        if (lane < 32) {
            float uu = kuc;
            #pragma unroll 16
            for (int s = 0; s < 64; ++s) uu = fmaf(KtL[cur][s][lane], xl[s], uu);
            ul[lane] = uu;
            outu[((size_t)b*T + t)*32 + lane] = uu;
        }
        __syncthreads();

        float xn = cl[lane];
        #pragma unroll 16
        for (int j = 0; j < 64; ++j) xn = fmaf(At[j][lane], xl[j], xn);
        #pragma unroll
        for (int w = 0; w < 32; ++w) xn = fmaf(Bt[w][lane], ul[w], xn);

        if (t+1 < T) {
            #pragma unroll
            for (int r = 0; r < 8; ++r) {
                const int idx = r*256 + lane*4;
                *(float4*)&KtL[cur^1][idx >> 5][idx & 31] = g[r];
            }
        }
        kuc = kun;
        __syncthreads();
        xl[lane] = xn;
        __syncthreads();
    }
}

// ---------------------------------------------------------------------------
extern "C" void kernel_launch(void* const* d_in, const int* in_sizes, int n_in,
                              void* d_out, int out_size, void* d_ws, size_t ws_size,
                              hipStream_t stream)
{
    const float* Q  = (const float*)d_in[0];
    const float* p  = (const float*)d_in[1];
    const float* A  = (const float*)d_in[2];
    const float* B  = (const float*)d_in[3];
    const float* c1 = (const float*)d_in[4];
    const float* x0 = (const float*)d_in[5];

    float* outx = (float*)d_out;                       // (NB,T,NS)
    float* outu = outx + (size_t)NB*T*NS;              // (NB,T,NC)
    float* outc = outu + (size_t)NB*T*NC;              // (NB,)

    lqr_bwd<<<NB, 512, 0, stream>>>(Q, p, A, B, c1, x0, outc);
    lqr_fwd<<<NB, 64, 0, stream>>>(A, B, c1, x0, outx, outu);
}

// Round 9
// 6005.364 us; speedup vs baseline: 1.9755x; 1.2783x over previous
//
#include <hip/hip_runtime.h>

#define NB 32
#define T 256
#define NS 64
#define NC 32
#define NSC 96

#define COMP(v,i) ((i)==0?(v).x:((i)==1?(v).y:((i)==2?(v).z:(v).w)))

static __device__ __forceinline__ float dot4(float4 a, float4 b){
    return fmaf(a.x,b.x, fmaf(a.y,b.y, fmaf(a.z,b.z, a.w*b.w)));
}

// Static device-global workspace; fully rewritten every call -> deterministic.
__device__ __align__(16) float g_KtG[(size_t)NB*T*NS*NC];   // [b][t][s][u], Kt[s][u]=K[u][s]
__device__ __align__(16) float g_kkG[(size_t)NB*T*NC];      // [b][t][u]

// ---------------------------------------------------------------------------
// Backward Riccati (policy-evaluation form; numerics = R5/R6/R8 passing runs).
// One block (512 threads) per batch. GEMM phases are 4x4 outer-product tiles:
// 2 x ds_read_b128 per k-iter for 16 FMA (LDS-pipe minimized, 7-8 waves busy).
// ---------------------------------------------------------------------------
__global__ __launch_bounds__(512, 2)
void lqr_bwd(const float* __restrict__ Qg_, const float* __restrict__ pg_,
             const float* __restrict__ Ag_, const float* __restrict__ Bg_,
             const float* __restrict__ c1g_, const float* __restrict__ x0g_,
             float* __restrict__ outc)
{
    __shared__ __align__(16) float Fo[64][100];  // F[s][j] (A|B), j<96
    __shared__ __align__(16) float V[64][68];    // carry V; holds Qxx between P2 and P6
    __shared__ __align__(16) float W[64][100];   // W = V*F
    __shared__ __align__(16) float Qxu[64][36];
    __shared__ __align__(16) float QuuC[32][36]; // Quu copy (survives GJ)
    __shared__ __align__(16) float Maug[32][68]; // P2: Quu in cols 0:32; GJ: Minv in cols 32:64
    __shared__ __align__(16) float Kt[64][36];   // Kt[s][u] = K[u][s]
    __shared__ __align__(16) float Rt[64][36];   // Rt[j][u] = Qux[u][j] + (Quu*K)[u][j]
    __shared__ __align__(16) float prow[2][64];  // GJ pivot row (double-buffered)
    __shared__ __align__(16) float pfac[2][32];  // GJ pivot column
    __shared__ __align__(16) float qh[96];
    __shared__ __align__(16) float gv[64];       // V*c1 + v
    __shared__ __align__(16) float hbuf[32];     // h = qu + Quu*kk
    __shared__ __align__(16) float c1l[64];
    __shared__ __align__(16) float vl[64];
    __shared__ __align__(16) float kkl[32];
    __shared__ __align__(16) float x0l[64];
    __shared__ float wAcc;

    const int tid = threadIdx.x;
    const int b   = blockIdx.x;

    const float* Qg = Qg_ + (size_t)b*T*NSC*NSC;
    const float* pg = pg_ + (size_t)b*T*NSC;
    const float* Ag = Ag_ + (size_t)b*NS*NS;
    const float* Bg = Bg_ + (size_t)b*NS*NC;
    float* KtG = g_KtG + (size_t)b*T*NS*NC;
    float* kkG = g_kkG + (size_t)b*T*NC;

    // ---- init
    for (int e = tid; e < NS*NS; e += 512) { int s = e>>6, j = e&63; Fo[s][j] = Ag[e]; }
    for (int e = tid; e < NS*NC; e += 512) { int s = e>>5, u = e&31; Fo[s][64+u] = Bg[e]; }
    for (int e = tid; e < 64*68; e += 512) ((float*)V)[e] = 0.f;
    if (tid < 64) { c1l[tid] = c1g_[b*64+tid]; vl[tid] = 0.f; x0l[tid] = x0g_[b*64+tid]; }
    if (tid == 0) wAcc = 0.f;
    __syncthreads();

    // GJ thread roles
    const int wq  = tid >> 4;          // 0..31 (GJ row)
    const int gjq = tid & 15, gj0 = gjq * 4;

    for (int t = T-1; t >= 0; --t) {
        const float* Qt = Qg + (size_t)t*NSC*NSC;
        const float* pt = pg + (size_t)t*NSC;

        // ---- P1: W[s0..+3][j0..+3] 4x4 tiles (384 thr);
        //      wave 6 (384..447): gv = V*c1 + v and wAcc += 0.5*c1'Vc1 + v'c1
        if (tid < 384) {
            const int s0 = (tid & 15) * 4;
            const int j0 = (tid >> 4) * 4;          // 0..92
            float acc[4][4] = {};
            for (int k = 0; k < 64; ++k) {
                const float4 v4 = *(const float4*)&V[k][s0];
                const float4 f4 = *(const float4*)&Fo[k][j0];
                #pragma unroll
                for (int r = 0; r < 4; ++r) {
                    const float vr = COMP(v4, r);
                    acc[r][0] = fmaf(vr, f4.x, acc[r][0]);
                    acc[r][1] = fmaf(vr, f4.y, acc[r][1]);
                    acc[r][2] = fmaf(vr, f4.z, acc[r][2]);
                    acc[r][3] = fmaf(vr, f4.w, acc[r][3]);
                }
            }
            #pragma unroll
            for (int r = 0; r < 4; ++r)
                *(float4*)&W[s0+r][j0] = make_float4(acc[r][0],acc[r][1],acc[r][2],acc[r][3]);
        } else if (tid < 448) {
            const int l = tid - 384;
            float d = 0.f;
            #pragma unroll
            for (int k4 = 0; k4 < 16; ++k4)
                d += dot4(*(const float4*)&V[l][k4*4], *(const float4*)&c1l[k4*4]);
            gv[l] = d + vl[l];
            float ps = c1l[l]*(0.5f*d + vl[l]);
            ps += __shfl_xor(ps,32); ps += __shfl_xor(ps,16); ps += __shfl_xor(ps,8);
            ps += __shfl_xor(ps,4);  ps += __shfl_xor(ps,2);  ps += __shfl_xor(ps,1);
            if (l == 0) wAcc += ps;
        }
        __syncthreads();

        // ---- P2: Qh = Qt + F'W, 4x4 tiles (448 thr: Qxx 256 / Qxu 128 / Quu 64);
        //      threads 448..511: qh = pt + F'gv. Qt prefetched to regs.
        if (tid < 448) {
            int i0, j0, osel;
            if (tid < 256)      { i0 = (tid & 15)*4;              j0 = (tid >> 4)*4;           osel = 0; }
            else if (tid < 384) { const int l = tid-256; i0 = (l & 15)*4;     j0 = 64 + (l >> 4)*4; osel = 1; }
            else                { const int l = tid-384; i0 = 64 + (l & 7)*4; j0 = 64 + (l >> 3)*4; osel = 2; }
            float4 qt[4];
            #pragma unroll
            for (int r = 0; r < 4; ++r)
                qt[r] = *(const float4*)&Qt[(size_t)(i0+r)*96 + j0];
            float acc[4][4] = {};
            for (int s = 0; s < 64; ++s) {
                const float4 f4 = *(const float4*)&Fo[s][i0];
                const float4 w4 = *(const float4*)&W[s][j0];
                #pragma unroll
                for (int r = 0; r < 4; ++r) {
                    const float fr = COMP(f4, r);
                    acc[r][0] = fmaf(fr, w4.x, acc[r][0]);
                    acc[r][1] = fmaf(fr, w4.y, acc[r][1]);
                    acc[r][2] = fmaf(fr, w4.z, acc[r][2]);
                    acc[r][3] = fmaf(fr, w4.w, acc[r][3]);
                }
            }
            #pragma unroll
            for (int r = 0; r < 4; ++r) {
                const float4 o = make_float4(acc[r][0]+qt[r].x, acc[r][1]+qt[r].y,
                                             acc[r][2]+qt[r].z, acc[r][3]+qt[r].w);
                if (osel == 0) {
                    *(float4*)&V[i0+r][j0] = o;          // Qxx in place (old V dead)
                } else if (osel == 1) {
                    *(float4*)&Qxu[i0+r][j0-64] = o;
                } else {
                    const int w = i0-64+r, u = j0-64;
                    *(float4*)&Maug[w][u] = o;
                    *(float4*)&QuuC[w][u] = o;
                    if (w == 0) {                         // stage GJ pivot-0 row
                        *(float4*)&prow[0][u] = o;
                        *(float4*)&prow[0][32+u] = (u == 0) ? make_float4(1.f,0.f,0.f,0.f)
                                                            : make_float4(0.f,0.f,0.f,0.f);
                    }
                    if (u == 0) pfac[0][w] = o.x;         // stage GJ pivot-0 col
                }
            }
        } else {
            const int l = tid - 448;
            float q0 = pt[l];
            float q1 = (l < 32) ? pt[64+l] : 0.f;
            for (int s = 0; s < 64; ++s) {
                const float g = gv[s];
                q0 = fmaf(Fo[s][l], g, q0);
                if (l < 32) q1 = fmaf(Fo[s][64+l], g, q1);
            }
            qh[l] = q0;
            if (l < 32) qh[64+l] = q1;
        }
        __syncthreads();

        // ---- P3: Gauss-Jordan of Quu, matrix-in-registers, 1 barrier/pivot (R8-proven)
        {
            float4 m;
            if (gjq < 8) m = *(const float4*)&Maug[wq][gj0];
            else {
                const int base = gj0 - 32;
                m.x = (base+0==wq)?1.f:0.f; m.y = (base+1==wq)?1.f:0.f;
                m.z = (base+2==wq)?1.f:0.f; m.w = (base+3==wq)?1.f:0.f;
            }
            #pragma unroll
            for (int k = 0; k < 32; ++k) {
                const int par = k & 1, nxt = par ^ 1;
                const float pinv = 1.0f / prow[par][k];
                const float4 pr = *(const float4*)&prow[par][gj0];
                if (wq == k) {
                    m.x = pr.x*pinv; m.y = pr.y*pinv; m.z = pr.z*pinv; m.w = pr.w*pinv;
                } else {
                    const float fac = pfac[par][wq]*pinv;
                    m.x = fmaf(-fac,pr.x,m.x); m.y = fmaf(-fac,pr.y,m.y);
                    m.z = fmaf(-fac,pr.z,m.z); m.w = fmaf(-fac,pr.w,m.w);
                }
                if (k < 31) {
                    if (wq == k+1) *(float4*)&prow[nxt][gj0] = m;
                    if (((k+1)>>2) == gjq) pfac[nxt][wq] = COMP(m,(k+1)&3);
                } else if (gjq >= 8) {
                    *(float4*)&Maug[wq][gj0] = m;          // Minv at cols 32:64
                }
                __syncthreads();
            }
        }

        // ---- P4: Kt[i][u] = -sum_w Qxu[i][w]*Minv[u][w]; kk = -Minv*qu
        {
            const int i = tid >> 3, u0 = (tid & 7) * 4;
            float a0=0,a1=0,a2=0,a3=0;
            #pragma unroll
            for (int w4 = 0; w4 < 8; ++w4) {
                const int wb = w4*4;
                const float4 q4 = *(const float4*)&Qxu[i][wb];
                const float4 m0 = *(const float4*)&Maug[u0+0][32+wb];
                const float4 m1 = *(const float4*)&Maug[u0+1][32+wb];
                const float4 m2 = *(const float4*)&Maug[u0+2][32+wb];
                const float4 m3 = *(const float4*)&Maug[u0+3][32+wb];
                a0 -= dot4(q4,m0); a1 -= dot4(q4,m1);
                a2 -= dot4(q4,m2); a3 -= dot4(q4,m3);
            }
            const float4 kt4 = make_float4(a0,a1,a2,a3);
            *(float4*)&Kt[i][u0] = kt4;
            *(float4*)&KtG[(size_t)t*2048 + i*32 + u0] = kt4;
            if (tid < 32) {
                float ka = 0.f;
                #pragma unroll
                for (int w4 = 0; w4 < 8; ++w4)
                    ka -= dot4(*(const float4*)&Maug[tid][32+w4*4], *(const float4*)&qh[64+w4*4]);
                kkl[tid] = ka;
                kkG[t*32 + tid] = ka;
            }
        }
        __syncthreads();

        // ---- P5: Rt[j][u] = Qxu[j][u] + sum_w QuuC[u][w]*Kt[j][w]; h = qu + Quu*kk
        {
            const int j = tid >> 3, u0 = (tid & 7) * 4;
            const float4 qx4 = *(const float4*)&Qxu[j][u0];
            float g0=qx4.x, g1=qx4.y, g2=qx4.z, g3=qx4.w;
            #pragma unroll
            for (int w4 = 0; w4 < 8; ++w4) {
                const int wb = w4*4;
                const float4 k4 = *(const float4*)&Kt[j][wb];
                g0 += dot4(*(const float4*)&QuuC[u0+0][wb], k4);
                g1 += dot4(*(const float4*)&QuuC[u0+1][wb], k4);
                g2 += dot4(*(const float4*)&QuuC[u0+2][wb], k4);
                g3 += dot4(*(const float4*)&QuuC[u0+3][wb], k4);
            }
            *(float4*)&Rt[j][u0] = make_float4(g0,g1,g2,g3);
            if (tid < 32) {
                float h = qh[64+tid];
                #pragma unroll
                for (int w4 = 0; w4 < 8; ++w4)
                    h += dot4(*(const float4*)&QuuC[tid][w4*4], *(const float4*)&kkl[w4*4]);
                hbuf[tid] = h;
            }
        }
        __syncthreads();

        // ---- P6 (512 thr): V <- Qxx + Qxu*K + K'(Qux + Quu*K); 4 rows x 2 cols each
        {
            const int jj = tid & 31, i0 = (tid >> 5) * 4;
            float aA[4], aB[4];
            #pragma unroll
            for (int r = 0; r < 4; ++r) { aA[r] = V[i0+r][jj]; aB[r] = V[i0+r][32+jj]; }
            #pragma unroll
            for (int u4 = 0; u4 < 8; ++u4) {
                const int ub = u4*4;
                const float4 kja = *(const float4*)&Kt[jj][ub];
                const float4 kjb = *(const float4*)&Kt[32+jj][ub];
                const float4 rja = *(const float4*)&Rt[jj][ub];
                const float4 rjb = *(const float4*)&Rt[32+jj][ub];
                #pragma unroll
                for (int r = 0; r < 4; ++r) {
                    const float4 xi = *(const float4*)&Qxu[i0+r][ub];
                    const float4 ki = *(const float4*)&Kt[i0+r][ub];
                    aA[r] += dot4(xi,kja) + dot4(ki,rja);
                    aB[r] += dot4(xi,kjb) + dot4(ki,rjb);
                }
            }
            #pragma unroll
            for (int r = 0; r < 4; ++r) { V[i0+r][jj] = aA[r]; V[i0+r][32+jj] = aB[r]; }
        }
        __syncthreads();

        // ---- symmetrize V (threads 0..447) ; vn + wAcc term (wave 7)
        if (tid < 448) {
            for (int e = tid; e < 4096; e += 448) {
                const int i = e >> 6, j = e & 63;
                if (i < j) {
                    const float av = 0.5f*(V[i][j] + V[j][i]);
                    V[i][j] = av; V[j][i] = av;
                }
            }
        } else {
            const int l = tid - 448;
            float vv = qh[l];
            #pragma unroll
            for (int u4 = 0; u4 < 8; ++u4) {
                vv += dot4(*(const float4*)&Qxu[l][u4*4], *(const float4*)&kkl[u4*4]);
                vv += dot4(*(const float4*)&Kt[l][u4*4],  *(const float4*)&hbuf[u4*4]);
            }
            vl[l] = vv;
            if (l < 32) {
                float r = kkl[l]*(hbuf[l] + qh[64+l]);
                r += __shfl_xor(r,16); r += __shfl_xor(r,8); r += __shfl_xor(r,4);
                r += __shfl_xor(r,2);  r += __shfl_xor(r,1);
                if (l == 0) wAcc += 0.5f*r;
            }
        }
        __syncthreads();
    }

    // ---- cost[b] = wAcc + 0.5*x0'V0 x0 + v0'x0
    if (tid < 64) {
        float rd = 0.f;
        #pragma unroll
        for (int k4 = 0; k4 < 16; ++k4)
            rd += dot4(*(const float4*)&V[tid][k4*4], *(const float4*)&x0l[k4*4]);
        float ps = x0l[tid]*(0.5f*rd + vl[tid]);
        ps += __shfl_xor(ps,32); ps += __shfl_xor(ps,16); ps += __shfl_xor(ps,8);
        ps += __shfl_xor(ps,4);  ps += __shfl_xor(ps,2);  ps += __shfl_xor(ps,1);
        if (tid == 0) outc[b] = wAcc + ps;
    }
}

// ---------------------------------------------------------------------------
// Forward rollout: 256 threads per batch; dot products split 4-way per output
// with shfl_xor reduction (dependency chains 16 vs 96); K(t+1) reg-prefetched.
// ---------------------------------------------------------------------------
__global__ __launch_bounds__(256)
void lqr_fwd(const float* __restrict__ Ag_, const float* __restrict__ Bg_,
             const float* __restrict__ c1g_, const float* __restrict__ x0g_,
             float* __restrict__ outx, float* __restrict__ outu)
{
    __shared__ __align__(16) float At[64][68];   // At[j][i] = A[i][j]
    __shared__ __align__(16) float Bt[32][68];   // Bt[w][i] = B[i][w]
    __shared__ __align__(16) float KtL[64][36];
    __shared__ float xl[64], ul[32], cl[64], kl[32], xnb[64];

    const int tid = threadIdx.x;
    const int b = blockIdx.x;

    const float* KtG = g_KtG + (size_t)b*T*NS*NC;
    const float* kkG = g_kkG + (size_t)b*T*NC;

    for (int e = tid; e < NS*NS; e += 256) At[e&63][e>>6] = Ag_[(size_t)b*4096 + e];
    for (int e = tid; e < NS*NC; e += 256) Bt[e&31][e>>5] = Bg_[(size_t)b*2048 + e];
    if (tid < 64) { xl[tid] = x0g_[b*64 + tid]; cl[tid] = c1g_[b*64 + tid]; }

    // prologue: stage K(0), kk(0)
    {
        const int i1 = tid*4, i2 = 1024 + tid*4;
        const float4 a = *(const float4*)&KtG[i1];
        const float4 c = *(const float4*)&KtG[i2];
        *(float4*)&KtL[i1>>5][i1&31] = a;
        *(float4*)&KtL[i2>>5][i2&31] = c;
        if (tid < 32) kl[tid] = kkG[tid];
    }
    __syncthreads();

    float4 g0, g1; float kn = 0.f;
    for (int t = 0; t < T; ++t) {
        // prefetch K(t+1) into regs (hidden under compute)
        if (t+1 < T) {
            g0 = *(const float4*)&KtG[(size_t)(t+1)*2048 + tid*4];
            g1 = *(const float4*)&KtG[(size_t)(t+1)*2048 + 1024 + tid*4];
            if (tid < 32) kn = kkG[(t+1)*32 + tid];
        }

        if (tid < 64) outx[((size_t)b*T + t)*64 + tid] = xl[tid];
        if (tid < 128) {
            const int u = tid >> 2, sp = tid & 3, s0 = sp*16;
            float r = 0.f;
            #pragma unroll
            for (int i = 0; i < 16; ++i) r = fmaf(KtL[s0+i][u], xl[s0+i], r);
            r += __shfl_xor(r, 1); r += __shfl_xor(r, 2);
            if (sp == 0) {
                const float uu = r + kl[u];
                ul[u] = uu;
                outu[((size_t)b*T + t)*32 + u] = uu;
            }
        }
        __syncthreads();

        {
            const int o = tid >> 2, sp = tid & 3;
            float r = 0.f;
            #pragma unroll
            for (int i = 0; i < 16; ++i) { const int j = sp*16 + i; r = fmaf(At[j][o], xl[j], r); }
            #pragma unroll
            for (int i = 0; i < 8; ++i)  { const int w = sp*8 + i;  r = fmaf(Bt[w][o], ul[w], r); }
            r += __shfl_xor(r, 1); r += __shfl_xor(r, 2);
            if (sp == 0) xnb[o] = r + cl[o];
        }
        __syncthreads();

        if (tid < 64) xl[tid] = xnb[tid];
        if (t+1 < T) {
            const int i1 = tid*4, i2 = 1024 + tid*4;
            *(float4*)&KtL[i1>>5][i1&31] = g0;
            *(float4*)&KtL[i2>>5][i2&31] = g1;
            if (tid < 32) kl[tid] = kn;
        }
        __syncthreads();
    }
}

// ---------------------------------------------------------------------------
extern "C" void kernel_launch(void* const* d_in, const int* in_sizes, int n_in,
                              void* d_out, int out_size, void* d_ws, size_t ws_size,
                              hipStream_t stream)
{
    const float* Q  = (const float*)d_in[0];
    const float* p  = (const float*)d_in[1];
    const float* A  = (const float*)d_in[2];
    const float* B  = (const float*)d_in[3];
    const float* c1 = (const float*)d_in[4];
    const float* x0 = (const float*)d_in[5];

    float* outx = (float*)d_out;                       // (NB,T,NS)
    float* outu = outx + (size_t)NB*T*NS;              // (NB,T,NC)
    float* outc = outu + (size_t)NB*T*NC;              // (NB,)

    lqr_bwd<<<NB, 512, 0, stream>>>(Q, p, A, B, c1, x0, outc);
    lqr_fwd<<<NB, 256, 0, stream>>>(A, B, c1, x0, outx, outu);
}